// Round 1
// baseline (279.529 us; speedup 1.0000x reference)
//
#include <hip/hip_runtime.h>
#include <hip/hip_bf16.h>

#define EPS 1e-8f

__device__ __forceinline__ float leaky(float x) { return x >= 0.f ? x : 0.1f * x; }

// block-wide reduce of (s,q) over 256 threads, atomicAdd into ds/dq.
__device__ __forceinline__ void reduce2_atomic(float s, float q, float* red,
                                               float* ds, float* dq) {
    #pragma unroll
    for (int off = 32; off > 0; off >>= 1) {
        s += __shfl_down(s, off, 64);
        q += __shfl_down(q, off, 64);
    }
    const int wid = threadIdx.x >> 6, lane = threadIdx.x & 63;
    if (lane == 0) { red[wid] = s; red[4 + wid] = q; }
    __syncthreads();
    if (threadIdx.x == 0) {
        atomicAdd(ds, red[0] + red[1] + red[2] + red[3]);
        atomicAdd(dq, red[4] + red[5] + red[6] + red[7]);
    }
}

// K1: a[b,c,t] = sum_f w2d[c,f] * feature[b,f,t]   (b=4, c=2, t=2000, f=128)
__global__ void k1_mix(const float* __restrict__ feature, const float* __restrict__ w2d,
                       float* __restrict__ a) {
    int idx = blockIdx.x * 256 + threadIdx.x;
    if (idx >= 4 * 2000) return;
    int b = idx / 2000, t = idx % 2000;
    float a0 = 0.f, a1 = 0.f;
    const float* fb = feature + (size_t)b * 128 * 2000 + t;
    #pragma unroll 4
    for (int f = 0; f < 128; f++) {
        float fv = fb[f * 2000];
        a0 = fmaf(w2d[f], fv, a0);
        a1 = fmaf(w2d[128 + f], fv, a1);
    }
    a[(b * 2 + 0) * 2000 + t] = a0;
    a[(b * 2 + 1) * 2000 + t] = a1;
}

// K2: d[b,p,t] = a0*mask[b,0,p,t] + a1*mask[b,1,p,t] + b2d ; fused stats0 (per-b sum,sumsq)
__global__ void k2_maskmix(const float* __restrict__ a, const float* __restrict__ mask,
                           const float* __restrict__ b2d, float* __restrict__ d,
                           float* __restrict__ stats0) {
    __shared__ float red[8];
    const int b = blockIdx.x / 1000;                 // 1000 blocks per batch elem
    const int i = (blockIdx.x % 1000) * 256 + threadIdx.x;  // i in [0, 128*2000)
    const int p = i / 2000, t = i % 2000;
    float a0 = a[(b * 2 + 0) * 2000 + t];
    float a1 = a[(b * 2 + 1) * 2000 + t];
    float m0 = mask[(((size_t)b * 2 + 0) * 128 + p) * 2000 + t];
    float m1 = mask[(((size_t)b * 2 + 1) * 128 + p) * 2000 + t];
    float v = fmaf(a0, m0, a1 * m1) + b2d[0];
    d[((size_t)b * 128 + p) * 2000 + t] = v;
    reduce2_atomic(v, v * v, red, &stats0[b * 2], &stats0[b * 2 + 1]);
}

// K3: conv1 128->256, k=3, s=2, pad=1 over T=2000 -> 1000. Input d normalized
// (LN0: per-batch scalar mean/var, scalar gamma/beta) + leaky on the fly.
// grid (1000/TT1, 4), 256 threads = output channel. Fused stats1.
#define TT1 4
__global__ void k3_conv1(const float* __restrict__ d, const float* __restrict__ stats0,
                         const float* __restrict__ g2d, const float* __restrict__ be2d,
                         const float* __restrict__ w1, const float* __restrict__ b1,
                         float* __restrict__ y1, float* __restrict__ stats1) {
    __shared__ float xs[128][2 * TT1 + 1];
    __shared__ float red[8];
    const int b = blockIdx.y;
    const int t0 = blockIdx.x * TT1;
    const int o = threadIdx.x;

    const float nrm = 1.f / 256000.f;
    float mean = stats0[b * 2] * nrm;
    float var  = fmaxf(stats0[b * 2 + 1] * nrm - mean * mean, 0.f);
    float inv  = rsqrtf(var + EPS);
    float g = g2d[0], be = be2d[0];

    const int base_in = 2 * t0 - 1;
    const int W = 2 * TT1 + 1;
    for (int e = threadIdx.x; e < 128 * W; e += 256) {
        int f = e / W, pos = e % W;
        int t = base_in + pos;
        float v = 0.f;
        if (t >= 0 && t < 2000) {
            float raw = d[((size_t)b * 128 + f) * 2000 + t];
            v = leaky(fmaf(g * inv, raw - mean, be));
        }
        xs[f][pos] = v;
    }
    __syncthreads();

    float acc[TT1];
    #pragma unroll
    for (int j = 0; j < TT1; j++) acc[j] = 0.f;
    const float* wo = w1 + o * 128 * 3;
    for (int f = 0; f < 128; f++) {
        float w0 = wo[f * 3 + 0], w1v = wo[f * 3 + 1], w2v = wo[f * 3 + 2];
        #pragma unroll
        for (int j = 0; j < TT1; j++) {
            acc[j] = fmaf(w0, xs[f][2 * j], acc[j]);
            acc[j] = fmaf(w1v, xs[f][2 * j + 1], acc[j]);
            acc[j] = fmaf(w2v, xs[f][2 * j + 2], acc[j]);
        }
    }
    float bias = b1[o];
    float s = 0.f, q = 0.f;
    #pragma unroll
    for (int j = 0; j < TT1; j++) {
        float v = acc[j] + bias;
        y1[((size_t)b * 256 + o) * 1000 + t0 + j] = v;
        s += v; q = fmaf(v, v, q);
    }
    reduce2_atomic(s, q, red, &stats1[b * 2], &stats1[b * 2 + 1]);
}

// K4: conv2 256->256, k=3, s=2, pad=1 over T=1000 -> 500. Input y1 normalized
// (LN1: per-batch mean/var, per-channel gamma/beta g1/bb1) + leaky on the fly.
#define TT2 5
__global__ void k4_conv2(const float* __restrict__ y1, const float* __restrict__ stats1,
                         const float* __restrict__ g1, const float* __restrict__ bb1,
                         const float* __restrict__ w2, const float* __restrict__ b2,
                         float* __restrict__ y2, float* __restrict__ stats2) {
    __shared__ float xs[256][2 * TT2 + 1];
    __shared__ float red[8];
    const int b = blockIdx.y;
    const int t0 = blockIdx.x * TT2;
    const int o = threadIdx.x;

    const float nrm = 1.f / 256000.f;
    float mean = stats1[b * 2] * nrm;
    float var  = fmaxf(stats1[b * 2 + 1] * nrm - mean * mean, 0.f);
    float inv  = rsqrtf(var + EPS);

    const int base_in = 2 * t0 - 1;
    const int W = 2 * TT2 + 1;
    for (int e = threadIdx.x; e < 256 * W; e += 256) {
        int f = e / W, pos = e % W;
        int t = base_in + pos;
        float v = 0.f;
        if (t >= 0 && t < 1000) {
            float raw = y1[((size_t)b * 256 + f) * 1000 + t];
            v = leaky(fmaf(g1[f] * inv, raw - mean, bb1[f]));
        }
        xs[f][pos] = v;
    }
    __syncthreads();

    float acc[TT2];
    #pragma unroll
    for (int j = 0; j < TT2; j++) acc[j] = 0.f;
    const float* wo = w2 + o * 256 * 3;
    for (int f = 0; f < 256; f++) {
        float w0 = wo[f * 3 + 0], w1v = wo[f * 3 + 1], w2v = wo[f * 3 + 2];
        #pragma unroll
        for (int j = 0; j < TT2; j++) {
            acc[j] = fmaf(w0, xs[f][2 * j], acc[j]);
            acc[j] = fmaf(w1v, xs[f][2 * j + 1], acc[j]);
            acc[j] = fmaf(w2v, xs[f][2 * j + 2], acc[j]);
        }
    }
    float bias = b2[o];
    float s = 0.f, q = 0.f;
    #pragma unroll
    for (int j = 0; j < TT2; j++) {
        float v = acc[j] + bias;
        y2[((size_t)b * 256 + o) * 500 + t0 + j] = v;
        s += v; q = fmaf(v, v, q);
    }
    reduce2_atomic(s, q, red, &stats2[b * 2], &stats2[b * 2 + 1]);
}

// K5: out[b,0,t] = b3 + sum_o w3[o] * leaky(LN2(y2[b,o,t]))   (500 t per b)
__global__ void k5_conv3(const float* __restrict__ y2, const float* __restrict__ stats2,
                         const float* __restrict__ g2, const float* __restrict__ bb2,
                         const float* __restrict__ w3, const float* __restrict__ b3,
                         float* __restrict__ out) {
    int idx = blockIdx.x * 256 + threadIdx.x;
    if (idx >= 4 * 500) return;
    int b = idx / 500, t = idx % 500;
    const float nrm = 1.f / 128000.f;
    float mean = stats2[b * 2] * nrm;
    float var  = fmaxf(stats2[b * 2 + 1] * nrm - mean * mean, 0.f);
    float inv  = rsqrtf(var + EPS);
    float acc = b3[0];
    const float* yb = y2 + (size_t)b * 256 * 500 + t;
    #pragma unroll 4
    for (int o = 0; o < 256; o++) {
        float raw = yb[o * 500];
        float xv = leaky(fmaf(g2[o] * inv, raw - mean, bb2[o]));
        acc = fmaf(w3[o], xv, acc);
    }
    out[idx] = acc;
}

extern "C" void kernel_launch(void* const* d_in, const int* in_sizes, int n_in,
                              void* d_out, int out_size, void* d_ws, size_t ws_size,
                              hipStream_t stream) {
    const float* feature = (const float*)d_in[0];
    const float* mask    = (const float*)d_in[1];
    const float* w2d     = (const float*)d_in[2];
    const float* b2d     = (const float*)d_in[3];
    const float* g2d     = (const float*)d_in[4];
    const float* be2d    = (const float*)d_in[5];
    const float* w1      = (const float*)d_in[6];
    const float* b1      = (const float*)d_in[7];
    const float* g1      = (const float*)d_in[8];
    const float* bb1     = (const float*)d_in[9];
    const float* w2      = (const float*)d_in[10];
    const float* b2      = (const float*)d_in[11];
    const float* g2      = (const float*)d_in[12];
    const float* bb2     = (const float*)d_in[13];
    const float* w3      = (const float*)d_in[14];
    const float* b3      = (const float*)d_in[15];
    float* out = (float*)d_out;

    float* ws = (float*)d_ws;
    // ws layout (floats): [0,24) stats (stats0/1/2, 8 each), pad to 32
    float* stats0 = ws + 0;
    float* stats1 = ws + 8;
    float* stats2 = ws + 16;
    float* a  = ws + 32;                    // 4*2*2000      = 16000
    float* d  = ws + 32 + 16000;            // 4*128*2000    = 1024000
    float* y1 = ws + 32 + 16000 + 1024000;  // 4*256*1000    = 1024000
    float* y2 = y1 + 1024000;               // 4*256*500     = 512000

    hipMemsetAsync(d_ws, 0, 32 * sizeof(float), stream);

    k1_mix<<<(8000 + 255) / 256, 256, 0, stream>>>(feature, w2d, a);
    k2_maskmix<<<4000, 256, 0, stream>>>(a, mask, b2d, d, stats0);
    k3_conv1<<<dim3(1000 / TT1, 4), 256, 0, stream>>>(d, stats0, g2d, be2d, w1, b1, y1, stats1);
    k4_conv2<<<dim3(500 / TT2, 4), 256, 0, stream>>>(y1, stats1, g1, bb1, w2, b2, y2, stats2);
    k5_conv3<<<(2000 + 255) / 256, 256, 0, stream>>>(y2, stats2, g2, bb2, w3, b3, out);
}

// Round 2
// 152.621 us; speedup vs baseline: 1.8315x; 1.8315x over previous
//
#include <hip/hip_runtime.h>
#include <hip/hip_bf16.h>

#define EPS 1e-8f

__device__ __forceinline__ float leaky(float x) { return x >= 0.f ? x : 0.1f * x; }

// Block-wide (256 thr) reduce of (s,q). Result valid on thread 0.
// Safe for repeated calls (leading barrier protects LDS reuse).
__device__ __forceinline__ void block_reduce2(float& s, float& q, float* red) {
    __syncthreads();
    #pragma unroll
    for (int off = 32; off > 0; off >>= 1) {
        s += __shfl_down(s, off, 64);
        q += __shfl_down(q, off, 64);
    }
    const int wid = threadIdx.x >> 6, lane = threadIdx.x & 63;
    if (lane == 0) { red[wid] = s; red[4 + wid] = q; }
    __syncthreads();
    if (threadIdx.x == 0) {
        s = red[0] + red[1] + red[2] + red[3];
        q = red[4] + red[5] + red[6] + red[7];
    }
}

// Reduce `n` partial (s,q) pairs (stride-2 base) -> mean/inv into stat[2].
__device__ __forceinline__ void stats_from_partials(const float* __restrict__ partials,
                                                    int n, float nrm,
                                                    float* red, float* stat) {
    float s = 0.f, q = 0.f;
    if ((int)threadIdx.x < n) {
        s = partials[threadIdx.x * 2];
        q = partials[threadIdx.x * 2 + 1];
    }
    block_reduce2(s, q, red);
    if (threadIdx.x == 0) {
        float mean = s * nrm;
        float var  = fmaxf(q * nrm - mean * mean, 0.f);
        stat[0] = mean;
        stat[1] = rsqrtf(var + EPS);
    }
    __syncthreads();
}

// K1: a[b,c,t] = sum_f w2d[c,f] * feature[b,f,t]   (b=4, c=2, t=2000, f=128)
__global__ void k1_mix(const float* __restrict__ feature, const float* __restrict__ w2d,
                       float* __restrict__ a) {
    int idx = blockIdx.x * 256 + threadIdx.x;
    if (idx >= 4 * 2000) return;
    int b = idx / 2000, t = idx % 2000;
    float a0 = 0.f, a1 = 0.f;
    const float* fb = feature + (size_t)b * 128 * 2000 + t;
    #pragma unroll 4
    for (int f = 0; f < 128; f++) {
        float fv = fb[f * 2000];
        a0 = fmaf(w2d[f], fv, a0);
        a1 = fmaf(w2d[128 + f], fv, a1);
    }
    a[(b * 2 + 0) * 2000 + t] = a0;
    a[(b * 2 + 1) * 2000 + t] = a1;
}

// K2: d[b,p,t] = a0*mask[b,0,p,t] + a1*mask[b,1,p,t] + b2d ; per-block partial stats.
// grid (250, 4): 1024 elements/block, 4/thread. partials0[b*256+blk] = (s,q).
__global__ void k2_maskmix(const float* __restrict__ a, const float* __restrict__ mask,
                           const float* __restrict__ b2d, float* __restrict__ d,
                           float* __restrict__ partials0) {
    __shared__ float red[8];
    const int b = blockIdx.y;
    const int base = blockIdx.x * 1024;
    const float bb = b2d[0];
    const float* a0p = a + (b * 2 + 0) * 2000;
    const float* a1p = a + (b * 2 + 1) * 2000;
    const float* m0p = mask + (size_t)(b * 2 + 0) * 128 * 2000;
    const float* m1p = mask + (size_t)(b * 2 + 1) * 128 * 2000;
    float* dp = d + (size_t)b * 128 * 2000;
    float s = 0.f, q = 0.f;
    #pragma unroll
    for (int j = 0; j < 4; j++) {
        int i = base + j * 256 + threadIdx.x;
        int t = i % 2000;
        float v = fmaf(a0p[t], m0p[i], a1p[t] * m1p[i]) + bb;
        dp[i] = v;
        s += v; q = fmaf(v, v, q);
    }
    block_reduce2(s, q, red);
    if (threadIdx.x == 0) {
        partials0[(b * 256 + blockIdx.x) * 2]     = s;
        partials0[(b * 256 + blockIdx.x) * 2 + 1] = q;
    }
}

// K3: conv1 128->256, k=3, s=2, pad=1, T=2000->1000. LN0+leaky applied on load.
// grid (250, 4), 256 thr = out channel. Writes partials1[b*256+blk].
#define TT1 4
__global__ void k3_conv1(const float* __restrict__ d, const float* __restrict__ partials0,
                         const float* __restrict__ g2d, const float* __restrict__ be2d,
                         const float* __restrict__ w1, const float* __restrict__ b1,
                         float* __restrict__ y1, float* __restrict__ partials1) {
    __shared__ float xs[128][2 * TT1 + 1];
    __shared__ float red[8];
    __shared__ float stat[2];
    const int b = blockIdx.y;
    const int t0 = blockIdx.x * TT1;
    const int o = threadIdx.x;

    stats_from_partials(partials0 + b * 512, 250, 1.f / 256000.f, red, stat);
    const float mean = stat[0], inv = stat[1];
    const float g = g2d[0], be = be2d[0];

    const int base_in = 2 * t0 - 1;
    const int W = 2 * TT1 + 1;
    for (int e = threadIdx.x; e < 128 * W; e += 256) {
        int f = e / W, pos = e % W;
        int t = base_in + pos;
        float v = 0.f;
        if (t >= 0 && t < 2000) {
            float raw = d[((size_t)b * 128 + f) * 2000 + t];
            v = leaky(fmaf(g * inv, raw - mean, be));
        }
        xs[f][pos] = v;
    }
    __syncthreads();

    float acc[TT1];
    #pragma unroll
    for (int j = 0; j < TT1; j++) acc[j] = 0.f;
    const float* wo = w1 + o * 128 * 3;
    for (int f = 0; f < 128; f++) {
        float w0 = wo[f * 3 + 0], w1v = wo[f * 3 + 1], w2v = wo[f * 3 + 2];
        #pragma unroll
        for (int j = 0; j < TT1; j++) {
            acc[j] = fmaf(w0, xs[f][2 * j], acc[j]);
            acc[j] = fmaf(w1v, xs[f][2 * j + 1], acc[j]);
            acc[j] = fmaf(w2v, xs[f][2 * j + 2], acc[j]);
        }
    }
    float bias = b1[o];
    float s = 0.f, q = 0.f;
    #pragma unroll
    for (int j = 0; j < TT1; j++) {
        float v = acc[j] + bias;
        y1[((size_t)b * 256 + o) * 1000 + t0 + j] = v;
        s += v; q = fmaf(v, v, q);
    }
    block_reduce2(s, q, red);
    if (threadIdx.x == 0) {
        partials1[(b * 256 + blockIdx.x) * 2]     = s;
        partials1[(b * 256 + blockIdx.x) * 2 + 1] = q;
    }
}

// K4: conv2 256->256, k=3, s=2, pad=1, T=1000->500. LN1 (per-ch g1/bb1)+leaky on load.
// grid (100, 4). Writes partials2[b*128+blk].
#define TT2 5
__global__ void k4_conv2(const float* __restrict__ y1, const float* __restrict__ partials1,
                         const float* __restrict__ g1, const float* __restrict__ bb1,
                         const float* __restrict__ w2, const float* __restrict__ b2,
                         float* __restrict__ y2, float* __restrict__ partials2) {
    __shared__ float xs[256][2 * TT2 + 1];
    __shared__ float red[8];
    __shared__ float stat[2];
    const int b = blockIdx.y;
    const int t0 = blockIdx.x * TT2;
    const int o = threadIdx.x;

    stats_from_partials(partials1 + b * 512, 250, 1.f / 256000.f, red, stat);
    const float mean = stat[0], inv = stat[1];

    const int base_in = 2 * t0 - 1;
    const int W = 2 * TT2 + 1;
    for (int e = threadIdx.x; e < 256 * W; e += 256) {
        int f = e / W, pos = e % W;
        int t = base_in + pos;
        float v = 0.f;
        if (t >= 0 && t < 1000) {
            float raw = y1[((size_t)b * 256 + f) * 1000 + t];
            v = leaky(fmaf(g1[f] * inv, raw - mean, bb1[f]));
        }
        xs[f][pos] = v;
    }
    __syncthreads();

    float acc[TT2];
    #pragma unroll
    for (int j = 0; j < TT2; j++) acc[j] = 0.f;
    const float* wo = w2 + o * 256 * 3;
    for (int f = 0; f < 256; f++) {
        float w0 = wo[f * 3 + 0], w1v = wo[f * 3 + 1], w2v = wo[f * 3 + 2];
        #pragma unroll
        for (int j = 0; j < TT2; j++) {
            acc[j] = fmaf(w0, xs[f][2 * j], acc[j]);
            acc[j] = fmaf(w1v, xs[f][2 * j + 1], acc[j]);
            acc[j] = fmaf(w2v, xs[f][2 * j + 2], acc[j]);
        }
    }
    float bias = b2[o];
    float s = 0.f, q = 0.f;
    #pragma unroll
    for (int j = 0; j < TT2; j++) {
        float v = acc[j] + bias;
        y2[((size_t)b * 256 + o) * 500 + t0 + j] = v;
        s += v; q = fmaf(v, v, q);
    }
    block_reduce2(s, q, red);
    if (threadIdx.x == 0) {
        partials2[(b * 128 + blockIdx.x) * 2]     = s;
        partials2[(b * 128 + blockIdx.x) * 2 + 1] = q;
    }
}

// K5: out[b,0,t] = b3 + sum_o w3[o] * leaky(LN2(y2[b,o,t])). grid (4,4), 125 t/block.
__global__ void k5_conv3(const float* __restrict__ y2, const float* __restrict__ partials2,
                         const float* __restrict__ g2, const float* __restrict__ bb2,
                         const float* __restrict__ w3, const float* __restrict__ b3,
                         float* __restrict__ out) {
    __shared__ float red[8];
    __shared__ float stat[2];
    const int b = blockIdx.y;
    const int t0 = blockIdx.x * 125;

    stats_from_partials(partials2 + b * 256, 100, 1.f / 128000.f, red, stat);
    const float mean = stat[0], inv = stat[1];

    if (threadIdx.x < 125) {
        int t = t0 + threadIdx.x;
        float acc = b3[0];
        const float* yb = y2 + (size_t)b * 256 * 500 + t;
        #pragma unroll 4
        for (int o = 0; o < 256; o++) {
            float raw = yb[o * 500];
            float xv = leaky(fmaf(g2[o] * inv, raw - mean, bb2[o]));
            acc = fmaf(w3[o], xv, acc);
        }
        out[b * 500 + t] = acc;
    }
}

extern "C" void kernel_launch(void* const* d_in, const int* in_sizes, int n_in,
                              void* d_out, int out_size, void* d_ws, size_t ws_size,
                              hipStream_t stream) {
    const float* feature = (const float*)d_in[0];
    const float* mask    = (const float*)d_in[1];
    const float* w2d     = (const float*)d_in[2];
    const float* b2d     = (const float*)d_in[3];
    const float* g2d     = (const float*)d_in[4];
    const float* be2d    = (const float*)d_in[5];
    const float* w1      = (const float*)d_in[6];
    const float* b1      = (const float*)d_in[7];
    const float* g1      = (const float*)d_in[8];
    const float* bb1     = (const float*)d_in[9];
    const float* w2      = (const float*)d_in[10];
    const float* b2      = (const float*)d_in[11];
    const float* g2      = (const float*)d_in[12];
    const float* bb2     = (const float*)d_in[13];
    const float* w3      = (const float*)d_in[14];
    const float* b3      = (const float*)d_in[15];
    float* out = (float*)d_out;

    float* ws = (float*)d_ws;
    // ws layout (floats):
    float* partials0 = ws;            // 4*256*2 = 2048
    float* partials1 = ws + 2048;     // 4*256*2 = 2048
    float* partials2 = ws + 4096;     // 4*128*2 = 1024
    float* a  = ws + 5120;            // 4*2*2000   = 16000
    float* d  = a + 16000;            // 4*128*2000 = 1024000
    float* y1 = d + 1024000;          // 4*256*1000 = 1024000
    float* y2 = y1 + 1024000;         // 4*256*500  = 512000

    k1_mix<<<(8000 + 255) / 256, 256, 0, stream>>>(feature, w2d, a);
    k2_maskmix<<<dim3(250, 4), 256, 0, stream>>>(a, mask, b2d, d, partials0);
    k3_conv1<<<dim3(250, 4), 256, 0, stream>>>(d, partials0, g2d, be2d, w1, b1, y1, partials1);
    k4_conv2<<<dim3(100, 4), 256, 0, stream>>>(y1, partials1, g1, bb1, w2, b2, y2, partials2);
    k5_conv3<<<dim3(4, 4), 256, 0, stream>>>(y2, partials2, g2, bb2, w3, b3, out);
}

// Round 3
// 133.596 us; speedup vs baseline: 2.0923x; 1.1424x over previous
//
#include <hip/hip_runtime.h>
#include <hip/hip_bf16.h>

#define EPS 1e-8f

__device__ __forceinline__ float leaky(float x) { return x >= 0.f ? x : 0.1f * x; }

// Block-wide (256 thr) reduce of (s,q). Result valid on thread 0.
__device__ __forceinline__ void block_reduce2(float& s, float& q, float* red) {
    __syncthreads();
    #pragma unroll
    for (int off = 32; off > 0; off >>= 1) {
        s += __shfl_down(s, off, 64);
        q += __shfl_down(q, off, 64);
    }
    const int wid = threadIdx.x >> 6, lane = threadIdx.x & 63;
    if (lane == 0) { red[wid] = s; red[4 + wid] = q; }
    __syncthreads();
    if (threadIdx.x == 0) {
        s = red[0] + red[1] + red[2] + red[3];
        q = red[4] + red[5] + red[6] + red[7];
    }
}

// Reduce n partial (s,q) pairs -> stat[0]=mean, stat[1]=rsqrt(var+EPS).
__device__ __forceinline__ void stats_from_partials(const float* __restrict__ partials,
                                                    int n, float nrm,
                                                    float* red, float* stat) {
    float s = 0.f, q = 0.f;
    if ((int)threadIdx.x < n) {
        s = partials[threadIdx.x * 2];
        q = partials[threadIdx.x * 2 + 1];
    }
    block_reduce2(s, q, red);
    if (threadIdx.x == 0) {
        float mean = s * nrm;
        float var  = fmaxf(q * nrm - mean * mean, 0.f);
        stat[0] = mean;
        stat[1] = rsqrtf(var + EPS);
    }
    __syncthreads();
}

// prep: transpose conv weights to [k][o] layout for coalesced loads.
// w1 [256][128*3] -> w1t [384][256]; w2 [256][256*3] -> w2t [768][256].
__global__ void kprep(const float* __restrict__ w1, const float* __restrict__ w2,
                      float* __restrict__ w1t, float* __restrict__ w2t) {
    int idx = blockIdx.x * 256 + threadIdx.x;   // coalesced WRITE index
    if (idx < 98304) {                           // w1t[idx]: r = idx/256, o = idx%256
        int r = idx >> 8, o = idx & 255;
        w1t[idx] = w1[o * 384 + r];
    }
    if (idx < 196608) {
        int r = idx >> 8, o = idx & 255;
        w2t[idx] = w2[o * 768 + r];
    }
}

// K1: a[b,c,t] = sum_f w2d[c,f] * feature[b,f,t]
__global__ void k1_mix(const float* __restrict__ feature, const float* __restrict__ w2d,
                       float* __restrict__ a) {
    int idx = blockIdx.x * 256 + threadIdx.x;
    if (idx >= 4 * 2000) return;
    int b = idx / 2000, t = idx % 2000;
    float a0 = 0.f, a1 = 0.f;
    const float* fb = feature + (size_t)b * 128 * 2000 + t;
    #pragma unroll 4
    for (int f = 0; f < 128; f++) {
        float fv = fb[f * 2000];
        a0 = fmaf(w2d[f], fv, a0);
        a1 = fmaf(w2d[128 + f], fv, a1);
    }
    a[(b * 2 + 0) * 2000 + t] = a0;
    a[(b * 2 + 1) * 2000 + t] = a1;
}

// K2: d = a0*mask0 + a1*mask1 + b2d ; per-block partial stats. grid (250,4).
__global__ void k2_maskmix(const float* __restrict__ a, const float* __restrict__ mask,
                           const float* __restrict__ b2d, float* __restrict__ d,
                           float* __restrict__ partials0) {
    __shared__ float red[8];
    const int b = blockIdx.y;
    const int base = blockIdx.x * 1024;
    const float bb = b2d[0];
    const float* a0p = a + (b * 2 + 0) * 2000;
    const float* a1p = a + (b * 2 + 1) * 2000;
    const float* m0p = mask + (size_t)(b * 2 + 0) * 128 * 2000;
    const float* m1p = mask + (size_t)(b * 2 + 1) * 128 * 2000;
    float* dp = d + (size_t)b * 128 * 2000;
    float s = 0.f, q = 0.f;
    #pragma unroll
    for (int j = 0; j < 4; j++) {
        int i = base + j * 256 + threadIdx.x;
        int t = i % 2000;
        float v = fmaf(a0p[t], m0p[i], a1p[t] * m1p[i]) + bb;
        dp[i] = v;
        s += v; q = fmaf(v, v, q);
    }
    block_reduce2(s, q, red);
    if (threadIdx.x == 0) {
        partials0[(b * 256 + blockIdx.x) * 2]     = s;
        partials0[(b * 256 + blockIdx.x) * 2 + 1] = q;
    }
}

// K3: conv1 128->256, k=3, s=2, pad=1, T=2000->1000. LN0+leaky on load.
// TT1=8 outputs/thread, grid (125,4), 256 thr = out channel.
// xs rows padded to 20 floats (80B) for aligned float4 broadcast reads.
#define TT1 8
template <bool TW>
__global__ void k3_conv1(const float* __restrict__ d, const float* __restrict__ partials0,
                         const float* __restrict__ g2d, const float* __restrict__ be2d,
                         const float* __restrict__ w1, const float* __restrict__ b1,
                         float* __restrict__ y1, float* __restrict__ partials1) {
    __shared__ float xs[128][20];   // window W=17, padded to 20
    __shared__ float red[8];
    __shared__ float stat[2];
    const int b = blockIdx.y;
    const int t0 = blockIdx.x * TT1;
    const int o = threadIdx.x;

    stats_from_partials(partials0 + b * 512, 250, 1.f / 256000.f, red, stat);
    const float mean = stat[0], inv = stat[1];
    const float g = g2d[0], be = be2d[0];

    const int base_in = 2 * t0 - 1;
    for (int e = threadIdx.x; e < 128 * 20; e += 256) {
        int f = e / 20, pos = e % 20;
        int t = base_in + pos;
        float v = 0.f;
        if (pos < 17 && t >= 0 && t < 2000) {
            float raw = d[((size_t)b * 128 + f) * 2000 + t];
            v = leaky(fmaf(g * inv, raw - mean, be));
        }
        xs[f][pos] = v;
    }
    __syncthreads();

    float acc[TT1];
    #pragma unroll
    for (int j = 0; j < TT1; j++) acc[j] = 0.f;
    #pragma unroll 2
    for (int f = 0; f < 128; f++) {
        float xv[20];
        const float4* xrow = (const float4*)&xs[f][0];
        *(float4*)&xv[0]  = xrow[0];
        *(float4*)&xv[4]  = xrow[1];
        *(float4*)&xv[8]  = xrow[2];
        *(float4*)&xv[12] = xrow[3];
        *(float4*)&xv[16] = xrow[4];
        float w0, w1v, w2v;
        if (TW) {
            const float* wf = w1 + f * 768;   // w1t[(f*3+k)][o]
            w0 = wf[o]; w1v = wf[256 + o]; w2v = wf[512 + o];
        } else {
            const float* wo = w1 + o * 384 + f * 3;
            w0 = wo[0]; w1v = wo[1]; w2v = wo[2];
        }
        #pragma unroll
        for (int j = 0; j < TT1; j++) {
            acc[j] = fmaf(w0, xv[2 * j], acc[j]);
            acc[j] = fmaf(w1v, xv[2 * j + 1], acc[j]);
            acc[j] = fmaf(w2v, xv[2 * j + 2], acc[j]);
        }
    }
    float bias = b1[o];
    float s = 0.f, q = 0.f;
    #pragma unroll
    for (int j = 0; j < TT1; j++) {
        float v = acc[j] + bias;
        y1[((size_t)b * 256 + o) * 1000 + t0 + j] = v;
        s += v; q = fmaf(v, v, q);
    }
    block_reduce2(s, q, red);
    if (threadIdx.x == 0) {
        partials1[(b * 256 + blockIdx.x) * 2]     = s;
        partials1[(b * 256 + blockIdx.x) * 2 + 1] = q;
    }
}

// K4: conv2 256->256, k=3, s=2, pad=1, T=1000->500. LN1 (per-ch)+leaky on load.
// TT2=5, grid (100,4). xs rows padded to 12 floats (48B).
#define TT2 5
template <bool TW>
__global__ void k4_conv2(const float* __restrict__ y1, const float* __restrict__ partials1,
                         const float* __restrict__ g1, const float* __restrict__ bb1,
                         const float* __restrict__ w2, const float* __restrict__ b2,
                         float* __restrict__ y2, float* __restrict__ partials2) {
    __shared__ float xs[256][12];   // window W=11, padded to 12
    __shared__ float red[8];
    __shared__ float stat[2];
    const int b = blockIdx.y;
    const int t0 = blockIdx.x * TT2;
    const int o = threadIdx.x;

    stats_from_partials(partials1 + b * 512, 125, 1.f / 256000.f, red, stat);
    const float mean = stat[0], inv = stat[1];

    const int base_in = 2 * t0 - 1;
    for (int e = threadIdx.x; e < 256 * 12; e += 256) {
        int f = e / 12, pos = e % 12;
        int t = base_in + pos;
        float v = 0.f;
        if (pos < 11 && t >= 0 && t < 1000) {
            float raw = y1[((size_t)b * 256 + f) * 1000 + t];
            v = leaky(fmaf(g1[f] * inv, raw - mean, bb1[f]));
        }
        xs[f][pos] = v;
    }
    __syncthreads();

    float acc[TT2];
    #pragma unroll
    for (int j = 0; j < TT2; j++) acc[j] = 0.f;
    #pragma unroll 2
    for (int f = 0; f < 256; f++) {
        float xv[12];
        const float4* xrow = (const float4*)&xs[f][0];
        *(float4*)&xv[0] = xrow[0];
        *(float4*)&xv[4] = xrow[1];
        *(float4*)&xv[8] = xrow[2];
        float w0, w1v, w2v;
        if (TW) {
            const float* wf = w2 + f * 768;   // w2t[(f*3+k)][o]
            w0 = wf[o]; w1v = wf[256 + o]; w2v = wf[512 + o];
        } else {
            const float* wo = w2 + o * 768 + f * 3;
            w0 = wo[0]; w1v = wo[1]; w2v = wo[2];
        }
        #pragma unroll
        for (int j = 0; j < TT2; j++) {
            acc[j] = fmaf(w0, xv[2 * j], acc[j]);
            acc[j] = fmaf(w1v, xv[2 * j + 1], acc[j]);
            acc[j] = fmaf(w2v, xv[2 * j + 2], acc[j]);
        }
    }
    float bias = b2[o];
    float s = 0.f, q = 0.f;
    #pragma unroll
    for (int j = 0; j < TT2; j++) {
        float v = acc[j] + bias;
        y2[((size_t)b * 256 + o) * 500 + t0 + j] = v;
        s += v; q = fmaf(v, v, q);
    }
    block_reduce2(s, q, red);
    if (threadIdx.x == 0) {
        partials2[(b * 128 + blockIdx.x) * 2]     = s;
        partials2[(b * 128 + blockIdx.x) * 2 + 1] = q;
    }
}

// K5: out[b,0,t] = b3 + sum_o w3[o] * leaky(LN2(y2[b,o,t])). grid (4,4).
__global__ void k5_conv3(const float* __restrict__ y2, const float* __restrict__ partials2,
                         const float* __restrict__ g2, const float* __restrict__ bb2,
                         const float* __restrict__ w3, const float* __restrict__ b3,
                         float* __restrict__ out) {
    __shared__ float red[8];
    __shared__ float stat[2];
    const int b = blockIdx.y;
    const int t0 = blockIdx.x * 125;

    stats_from_partials(partials2 + b * 256, 100, 1.f / 128000.f, red, stat);
    const float mean = stat[0], inv = stat[1];

    if (threadIdx.x < 125) {
        int t = t0 + threadIdx.x;
        float acc = b3[0];
        const float* yb = y2 + (size_t)b * 256 * 500 + t;
        #pragma unroll 4
        for (int o = 0; o < 256; o++) {
            float raw = yb[o * 500];
            float xv = leaky(fmaf(g2[o] * inv, raw - mean, bb2[o]));
            acc = fmaf(w3[o], xv, acc);
        }
        out[b * 500 + t] = acc;
    }
}

extern "C" void kernel_launch(void* const* d_in, const int* in_sizes, int n_in,
                              void* d_out, int out_size, void* d_ws, size_t ws_size,
                              hipStream_t stream) {
    const float* feature = (const float*)d_in[0];
    const float* mask    = (const float*)d_in[1];
    const float* w2d     = (const float*)d_in[2];
    const float* b2d     = (const float*)d_in[3];
    const float* g2d     = (const float*)d_in[4];
    const float* be2d    = (const float*)d_in[5];
    const float* w1      = (const float*)d_in[6];
    const float* b1      = (const float*)d_in[7];
    const float* g1      = (const float*)d_in[8];
    const float* bb1     = (const float*)d_in[9];
    const float* w2      = (const float*)d_in[10];
    const float* b2      = (const float*)d_in[11];
    const float* g2      = (const float*)d_in[12];
    const float* bb2     = (const float*)d_in[13];
    const float* w3      = (const float*)d_in[14];
    const float* b3      = (const float*)d_in[15];
    float* out = (float*)d_out;

    float* ws = (float*)d_ws;
    // ws layout (floats):
    float* partials0 = ws;            // 2048
    float* partials1 = ws + 2048;     // 2048
    float* partials2 = ws + 4096;     // 1024
    float* a   = ws + 5120;           // 16000
    float* d   = a + 16000;           // 1,024,000
    float* y1  = d + 1024000;         // 1,024,000
    float* y2  = y1 + 1024000;        // 512,000
    float* w1t = y2 + 512000;         // 98,304
    float* w2t = w1t + 98304;         // 196,608
    const size_t need_bytes = (size_t)(5120 + 16000 + 1024000 + 1024000 + 512000
                                       + 98304 + 196608) * sizeof(float);
    const bool trans = ws_size >= need_bytes;

    if (trans)
        kprep<<<768, 256, 0, stream>>>(w1, w2, w1t, w2t);
    k1_mix<<<(8000 + 255) / 256, 256, 0, stream>>>(feature, w2d, a);
    k2_maskmix<<<dim3(250, 4), 256, 0, stream>>>(a, mask, b2d, d, partials0);
    if (trans) {
        k3_conv1<true><<<dim3(125, 4), 256, 0, stream>>>(d, partials0, g2d, be2d, w1t, b1, y1, partials1);
        k4_conv2<true><<<dim3(100, 4), 256, 0, stream>>>(y1, partials1, g1, bb1, w2t, b2, y2, partials2);
    } else {
        k3_conv1<false><<<dim3(125, 4), 256, 0, stream>>>(d, partials0, g2d, be2d, w1, b1, y1, partials1);
        k4_conv2<false><<<dim3(100, 4), 256, 0, stream>>>(y1, partials1, g1, bb1, w2, b2, y2, partials2);
    }
    k5_conv3<<<dim3(4, 4), 256, 0, stream>>>(y2, partials2, g2, bb2, w3, b3, out);
}

// Round 4
// 107.626 us; speedup vs baseline: 2.5972x; 1.2413x over previous
//
#include <hip/hip_runtime.h>
#include <hip/hip_bf16.h>

#define EPS 1e-8f

typedef unsigned short ushortT;
typedef unsigned int uintT;

__device__ __forceinline__ float leaky(float x) { return x >= 0.f ? x : 0.1f * x; }

__device__ __forceinline__ ushortT f2bf(float v) {
    uintT u = __float_as_uint(v);
    uintT r = (u + 0x7fffu + ((u >> 16) & 1u)) >> 16;
    return (ushortT)r;
}

// Block-wide (256 thr) reduce of (s,q). Result valid on thread 0.
__device__ __forceinline__ void block_reduce2(float& s, float& q, float* red) {
    __syncthreads();
    #pragma unroll
    for (int off = 32; off > 0; off >>= 1) {
        s += __shfl_down(s, off, 64);
        q += __shfl_down(q, off, 64);
    }
    const int wid = threadIdx.x >> 6, lane = threadIdx.x & 63;
    if (lane == 0) { red[wid] = s; red[4 + wid] = q; }
    __syncthreads();
    if (threadIdx.x == 0) {
        s = red[0] + red[1] + red[2] + red[3];
        q = red[4] + red[5] + red[6] + red[7];
    }
}

// Reduce n partial (s,q) pairs -> stat[0]=mean, stat[1]=rsqrt(var+EPS).
__device__ __forceinline__ void stats_from_partials(const float* __restrict__ partials,
                                                    int n, float nrm,
                                                    float* red, float* stat) {
    float s = 0.f, q = 0.f;
    if ((int)threadIdx.x < n) {
        s = partials[threadIdx.x * 2];
        q = partials[threadIdx.x * 2 + 1];
    }
    block_reduce2(s, q, red);
    if (threadIdx.x == 0) {
        float mean = s * nrm;
        float var  = fmaxf(q * nrm - mean * mean, 0.f);
        stat[0] = mean;
        stat[1] = rsqrtf(var + EPS);
    }
    __syncthreads();
}

// prep: weights -> bf16, tap-packed layout wp[(f*256+o)*4 + k], k=3 padded 0.
__global__ void kprep(const float* __restrict__ w1, const float* __restrict__ w2,
                      ushortT* __restrict__ w1p, ushortT* __restrict__ w2p) {
    int idx = blockIdx.x * 256 + threadIdx.x;
    if (idx < 98304) {               // w1 [256][384] read-coalesced
        int o = idx / 384, r = idx % 384;
        int f = r / 3, k = r % 3;
        w1p[(((f << 8) + o) << 2) + k] = f2bf(w1[idx]);
    }
    if (idx < 32768) w1p[(idx << 2) + 3] = 0;
    if (idx < 196608) {              // w2 [256][768]
        int o = idx / 768, r = idx % 768;
        int f = r / 3, k = r % 3;
        w2p[(((f << 8) + o) << 2) + k] = f2bf(w2[idx]);
    }
    if (idx < 65536) w2p[(idx << 2) + 3] = 0;
}

// K1: a[b,c,t] = sum_f w2d[c,f] * feature[b,f,t]. grid (63,4); 8 f-chunks x 32 t.
__global__ void k1_mix(const float* __restrict__ feature, const float* __restrict__ w2d,
                       float* __restrict__ a) {
    __shared__ float r0[8][33];
    __shared__ float r1[8][33];
    const int b = blockIdx.y;
    const int tl = threadIdx.x & 31;
    const int fc = threadIdx.x >> 5;
    const int t = blockIdx.x * 32 + tl;
    float s0 = 0.f, s1 = 0.f;
    if (t < 2000) {
        const float* fb = feature + ((size_t)b * 128 + fc * 16) * 2000 + t;
        const float* wa = w2d + fc * 16;
        const float* wb = w2d + 128 + fc * 16;
        #pragma unroll
        for (int i = 0; i < 16; i++) {
            float fv = fb[i * 2000];
            s0 = fmaf(wa[i], fv, s0);
            s1 = fmaf(wb[i], fv, s1);
        }
    }
    r0[fc][tl] = s0;
    r1[fc][tl] = s1;
    __syncthreads();
    if (fc == 0 && t < 2000) {
        float acc0 = 0.f, acc1 = 0.f;
        #pragma unroll
        for (int i = 0; i < 8; i++) { acc0 += r0[i][tl]; acc1 += r1[i][tl]; }
        a[(b * 2 + 0) * 2000 + t] = acc0;
        a[(b * 2 + 1) * 2000 + t] = acc1;
    }
}

// K2: d = a0*mask0 + a1*mask1 + b2d ; float4; per-block partial stats. grid (250,4).
__global__ void k2_maskmix(const float* __restrict__ a, const float* __restrict__ mask,
                           const float* __restrict__ b2d, float* __restrict__ d,
                           float* __restrict__ partials0) {
    __shared__ float red[8];
    const int b = blockIdx.y;
    const int i0 = (blockIdx.x * 256 + threadIdx.x) * 4;
    const float bb = b2d[0];
    const float* a0p = a + (b * 2 + 0) * 2000;
    const float* a1p = a + (b * 2 + 1) * 2000;
    const float4 m0 = *(const float4*)(mask + (size_t)(b * 2 + 0) * 256000 + i0);
    const float4 m1 = *(const float4*)(mask + (size_t)(b * 2 + 1) * 256000 + i0);
    float* dp = d + (size_t)b * 256000;
    float mv0[4] = {m0.x, m0.y, m0.z, m0.w};
    float mv1[4] = {m1.x, m1.y, m1.z, m1.w};
    float dv[4];
    float s = 0.f, q = 0.f;
    #pragma unroll
    for (int j = 0; j < 4; j++) {
        int t = (i0 + j) % 2000;
        float v = fmaf(a0p[t], mv0[j], a1p[t] * mv1[j]) + bb;
        dv[j] = v;
        s += v; q = fmaf(v, v, q);
    }
    *(float4*)(dp + i0) = *(float4*)dv;
    block_reduce2(s, q, red);
    if (threadIdx.x == 0) {
        partials0[(b * 256 + blockIdx.x) * 2]     = s;
        partials0[(b * 256 + blockIdx.x) * 2 + 1] = q;
    }
}

// K3: conv1 128->256, k=3, s=2, pad=1, T=2000->1000. LN0+leaky on load.
// TT1=8, grid (125,4), thread = out channel. bf16 tap-packed weights when TW.
#define TT1 8
template <bool TW>
__global__ void k3_conv1(const float* __restrict__ d, const float* __restrict__ partials0,
                         const float* __restrict__ g2d, const float* __restrict__ be2d,
                         const void* __restrict__ w1, const float* __restrict__ b1,
                         float* __restrict__ y1, float* __restrict__ partials1) {
    __shared__ float xs[128][20];   // window W=17, padded to 20
    __shared__ float red[8];
    __shared__ float stat[2];
    const int b = blockIdx.y;
    const int t0 = blockIdx.x * TT1;
    const int o = threadIdx.x;

    stats_from_partials(partials0 + b * 512, 250, 1.f / 256000.f, red, stat);
    const float mean = stat[0], inv = stat[1];
    const float g = g2d[0], be = be2d[0];

    const int base_in = 2 * t0 - 1;
    for (int e = threadIdx.x; e < 128 * 20; e += 256) {
        int f = e / 20, pos = e % 20;
        int t = base_in + pos;
        float v = 0.f;
        if (pos < 17 && t >= 0 && t < 2000) {
            float raw = d[((size_t)b * 128 + f) * 2000 + t];
            v = leaky(fmaf(g * inv, raw - mean, be));
        }
        xs[f][pos] = v;
    }
    __syncthreads();

    float acc[TT1];
    #pragma unroll
    for (int j = 0; j < TT1; j++) acc[j] = 0.f;
    #pragma unroll 4
    for (int f = 0; f < 128; f++) {
        float xv[20];
        const float4* xrow = (const float4*)&xs[f][0];
        *(float4*)&xv[0]  = xrow[0];
        *(float4*)&xv[4]  = xrow[1];
        *(float4*)&xv[8]  = xrow[2];
        *(float4*)&xv[12] = xrow[3];
        *(float4*)&xv[16] = xrow[4];
        float w0, w1v, w2v;
        if (TW) {
            const ushortT* wr = (const ushortT*)w1 + (((f << 8) + o) << 2);
            uint2 wp = *(const uint2*)wr;
            w0  = __uint_as_float(wp.x << 16);
            w1v = __uint_as_float(wp.x & 0xffff0000u);
            w2v = __uint_as_float(wp.y << 16);
        } else {
            const float* wo = (const float*)w1 + o * 384 + f * 3;
            w0 = wo[0]; w1v = wo[1]; w2v = wo[2];
        }
        #pragma unroll
        for (int j = 0; j < TT1; j++) {
            acc[j] = fmaf(w0, xv[2 * j], acc[j]);
            acc[j] = fmaf(w1v, xv[2 * j + 1], acc[j]);
            acc[j] = fmaf(w2v, xv[2 * j + 2], acc[j]);
        }
    }
    float bias = b1[o];
    float s = 0.f, q = 0.f;
    #pragma unroll
    for (int j = 0; j < TT1; j++) {
        float v = acc[j] + bias;
        y1[((size_t)b * 256 + o) * 1000 + t0 + j] = v;
        s += v; q = fmaf(v, v, q);
    }
    block_reduce2(s, q, red);
    if (threadIdx.x == 0) {
        partials1[(b * 256 + blockIdx.x) * 2]     = s;
        partials1[(b * 256 + blockIdx.x) * 2 + 1] = q;
    }
}

// K4: conv2 256->256, k=3, s=2, pad=1, T=1000->500. LN1 (per-ch)+leaky on load.
// TT2=4, grid (125,4).
#define TT2 4
template <bool TW>
__global__ void k4_conv2(const float* __restrict__ y1, const float* __restrict__ partials1,
                         const float* __restrict__ g1, const float* __restrict__ bb1,
                         const void* __restrict__ w2, const float* __restrict__ b2,
                         float* __restrict__ y2, float* __restrict__ partials2) {
    __shared__ float xs[256][12];   // window W=9, padded to 12
    __shared__ float red[8];
    __shared__ float stat[2];
    const int b = blockIdx.y;
    const int t0 = blockIdx.x * TT2;
    const int o = threadIdx.x;

    stats_from_partials(partials1 + b * 512, 125, 1.f / 256000.f, red, stat);
    const float mean = stat[0], inv = stat[1];

    const int base_in = 2 * t0 - 1;
    for (int e = threadIdx.x; e < 256 * 12; e += 256) {
        int f = e / 12, pos = e % 12;
        int t = base_in + pos;
        float v = 0.f;
        if (pos < 9 && t >= 0 && t < 1000) {
            float raw = y1[((size_t)b * 256 + f) * 1000 + t];
            v = leaky(fmaf(g1[f] * inv, raw - mean, bb1[f]));
        }
        xs[f][pos] = v;
    }
    __syncthreads();

    float acc[TT2];
    #pragma unroll
    for (int j = 0; j < TT2; j++) acc[j] = 0.f;
    #pragma unroll 4
    for (int f = 0; f < 256; f++) {
        float xv[12];
        const float4* xrow = (const float4*)&xs[f][0];
        *(float4*)&xv[0] = xrow[0];
        *(float4*)&xv[4] = xrow[1];
        *(float4*)&xv[8] = xrow[2];
        float w0, w1v, w2v;
        if (TW) {
            const ushortT* wr = (const ushortT*)w2 + (((f << 8) + o) << 2);
            uint2 wp = *(const uint2*)wr;
            w0  = __uint_as_float(wp.x << 16);
            w1v = __uint_as_float(wp.x & 0xffff0000u);
            w2v = __uint_as_float(wp.y << 16);
        } else {
            const float* wo = (const float*)w2 + o * 768 + f * 3;
            w0 = wo[0]; w1v = wo[1]; w2v = wo[2];
        }
        #pragma unroll
        for (int j = 0; j < TT2; j++) {
            acc[j] = fmaf(w0, xv[2 * j], acc[j]);
            acc[j] = fmaf(w1v, xv[2 * j + 1], acc[j]);
            acc[j] = fmaf(w2v, xv[2 * j + 2], acc[j]);
        }
    }
    float bias = b2[o];
    float s = 0.f, q = 0.f;
    #pragma unroll
    for (int j = 0; j < TT2; j++) {
        float v = acc[j] + bias;
        y2[((size_t)b * 256 + o) * 500 + t0 + j] = v;
        s += v; q = fmaf(v, v, q);
    }
    block_reduce2(s, q, red);
    if (threadIdx.x == 0) {
        partials2[(b * 128 + blockIdx.x) * 2]     = s;
        partials2[(b * 128 + blockIdx.x) * 2 + 1] = q;
    }
}

// K5: out[b,0,t] = b3 + sum_o w3[o] * leaky(LN2(y2[b,o,t])). grid (4,4).
__global__ void k5_conv3(const float* __restrict__ y2, const float* __restrict__ partials2,
                         const float* __restrict__ g2, const float* __restrict__ bb2,
                         const float* __restrict__ w3, const float* __restrict__ b3,
                         float* __restrict__ out) {
    __shared__ float red[8];
    __shared__ float stat[2];
    const int b = blockIdx.y;
    const int t0 = blockIdx.x * 125;

    stats_from_partials(partials2 + b * 256, 125, 1.f / 128000.f, red, stat);
    const float mean = stat[0], inv = stat[1];

    if (threadIdx.x < 125) {
        int t = t0 + threadIdx.x;
        float acc = b3[0];
        const float* yb = y2 + (size_t)b * 256 * 500 + t;
        #pragma unroll 4
        for (int o = 0; o < 256; o++) {
            float raw = yb[o * 500];
            float xv = leaky(fmaf(g2[o] * inv, raw - mean, bb2[o]));
            acc = fmaf(w3[o], xv, acc);
        }
        out[b * 500 + t] = acc;
    }
}

extern "C" void kernel_launch(void* const* d_in, const int* in_sizes, int n_in,
                              void* d_out, int out_size, void* d_ws, size_t ws_size,
                              hipStream_t stream) {
    const float* feature = (const float*)d_in[0];
    const float* mask    = (const float*)d_in[1];
    const float* w2d     = (const float*)d_in[2];
    const float* b2d     = (const float*)d_in[3];
    const float* g2d     = (const float*)d_in[4];
    const float* be2d    = (const float*)d_in[5];
    const float* w1      = (const float*)d_in[6];
    const float* b1      = (const float*)d_in[7];
    const float* g1      = (const float*)d_in[8];
    const float* bb1     = (const float*)d_in[9];
    const float* w2      = (const float*)d_in[10];
    const float* b2      = (const float*)d_in[11];
    const float* g2      = (const float*)d_in[12];
    const float* bb2     = (const float*)d_in[13];
    const float* w3      = (const float*)d_in[14];
    const float* b3      = (const float*)d_in[15];
    float* out = (float*)d_out;

    float* ws = (float*)d_ws;
    // ws layout (floats):
    float* partials0 = ws;            // 2048
    float* partials1 = ws + 2048;     // 2048
    float* partials2 = ws + 4096;     // 1024
    float* a   = ws + 5120;           // 16000
    float* d   = a + 16000;           // 1,024,000
    float* y1  = d + 1024000;         // 1,024,000
    float* y2  = y1 + 1024000;        // 512,000
    ushortT* w1p = (ushortT*)(y2 + 512000);   // 131072 ushorts (= 65536 floats)
    ushortT* w2p = w1p + 131072;              // 262144 ushorts (= 131072 floats)
    const size_t need_bytes = (size_t)(5120 + 16000 + 1024000 + 1024000 + 512000
                                       + 65536 + 131072) * sizeof(float);
    const bool trans = ws_size >= need_bytes;

    if (trans)
        kprep<<<768, 256, 0, stream>>>(w1, w2, w1p, w2p);
    k1_mix<<<dim3(63, 4), 256, 0, stream>>>(feature, w2d, a);
    k2_maskmix<<<dim3(250, 4), 256, 0, stream>>>(a, mask, b2d, d, partials0);
    if (trans) {
        k3_conv1<true><<<dim3(125, 4), 256, 0, stream>>>(d, partials0, g2d, be2d, w1p, b1, y1, partials1);
        k4_conv2<true><<<dim3(125, 4), 256, 0, stream>>>(y1, partials1, g1, bb1, w2p, b2, y2, partials2);
    } else {
        k3_conv1<false><<<dim3(125, 4), 256, 0, stream>>>(d, partials0, g2d, be2d, w1, b1, y1, partials1);
        k4_conv2<false><<<dim3(125, 4), 256, 0, stream>>>(y1, partials1, g1, bb1, w2, b2, y2, partials2);
    }
    k5_conv3<<<dim3(4, 4), 256, 0, stream>>>(y2, partials2, g2, bb2, w3, b3, out);
}

// Round 5
// 73.524 us; speedup vs baseline: 3.8018x; 1.4638x over previous
//
#include <hip/hip_runtime.h>
#include <hip/hip_bf16.h>

#define EPS 1e-8f

typedef unsigned short ushortT;
typedef __bf16 bf16x8 __attribute__((ext_vector_type(8)));
typedef float f32x4 __attribute__((ext_vector_type(4)));

union B8 { uint4 u; bf16x8 v; };

__device__ __forceinline__ float leaky(float x) { return x >= 0.f ? x : 0.1f * x; }

__device__ __forceinline__ ushortT f2bf(float v) {
    unsigned u = __float_as_uint(v);
    return (ushortT)((u + 0x7fffu + ((u >> 16) & 1u)) >> 16);
}

// Block-wide (256 thr) reduce of (s,q). Result valid on thread 0.
__device__ __forceinline__ void block_reduce2(float& s, float& q, float* red) {
    __syncthreads();
    #pragma unroll
    for (int off = 32; off > 0; off >>= 1) {
        s += __shfl_down(s, off, 64);
        q += __shfl_down(q, off, 64);
    }
    const int wid = threadIdx.x >> 6, lane = threadIdx.x & 63;
    if (lane == 0) { red[wid] = s; red[4 + wid] = q; }
    __syncthreads();
    if (threadIdx.x == 0) {
        s = red[0] + red[1] + red[2] + red[3];
        q = red[4] + red[5] + red[6] + red[7];
    }
}

__device__ __forceinline__ void stats_from_partials(const float* __restrict__ partials,
                                                    int n, float nrm,
                                                    float* red, float* stat) {
    float s = 0.f, q = 0.f;
    if ((int)threadIdx.x < n) {
        s = partials[threadIdx.x * 2];
        q = partials[threadIdx.x * 2 + 1];
    }
    block_reduce2(s, q, red);
    if (threadIdx.x == 0) {
        float mean = s * nrm;
        float var  = fmaxf(q * nrm - mean * mean, 0.f);
        stat[0] = mean;
        stat[1] = rsqrtf(var + EPS);
    }
    __syncthreads();
}

// K1 (+fused weight prep): blocks x<63 compute a[b,c,t]; x>=63 cast W to bf16.
// w1b[o*384 + k], w2b[o*768 + k] flat bf16 (k = f*3+kk, exactly source order).
__global__ void k1_mix(const float* __restrict__ feature, const float* __restrict__ w2d,
                       float* __restrict__ a,
                       const float* __restrict__ w1, const float* __restrict__ w2,
                       ushortT* __restrict__ w1b, ushortT* __restrict__ w2b) {
    if (blockIdx.x >= 63) {   // prep: 72*4 = 288 chunks of 1024 floats
        int p = (blockIdx.x - 63) * 4 + blockIdx.y;
        int base = (p < 96 ? p : p - 96) * 1024 + threadIdx.x * 4;
        const float* src = (p < 96) ? (w1 + base) : (w2 + base);
        ushortT* dst = (p < 96) ? (w1b + base) : (w2b + base);
        float4 v = *(const float4*)src;
        ushort4 o;
        o.x = f2bf(v.x); o.y = f2bf(v.y); o.z = f2bf(v.z); o.w = f2bf(v.w);
        *(ushort4*)dst = o;
        return;
    }
    __shared__ float r0[8][33];
    __shared__ float r1[8][33];
    const int b = blockIdx.y;
    const int tl = threadIdx.x & 31;
    const int fc = threadIdx.x >> 5;
    const int t = blockIdx.x * 32 + tl;
    float s0 = 0.f, s1 = 0.f;
    if (t < 2000) {
        const float* fb = feature + ((size_t)b * 128 + fc * 16) * 2000 + t;
        const float* wa = w2d + fc * 16;
        const float* wb = w2d + 128 + fc * 16;
        #pragma unroll
        for (int i = 0; i < 16; i++) {
            float fv = fb[i * 2000];
            s0 = fmaf(wa[i], fv, s0);
            s1 = fmaf(wb[i], fv, s1);
        }
    }
    r0[fc][tl] = s0;
    r1[fc][tl] = s1;
    __syncthreads();
    if (fc == 0 && t < 2000) {
        float acc0 = 0.f, acc1 = 0.f;
        #pragma unroll
        for (int i = 0; i < 8; i++) { acc0 += r0[i][tl]; acc1 += r1[i][tl]; }
        a[(b * 2 + 0) * 2000 + t] = acc0;
        a[(b * 2 + 1) * 2000 + t] = acc1;
    }
}

// K2: d = a0*mask0 + a1*mask1 + b2d ; float4; partial stats. grid (250,4).
__global__ void k2_maskmix(const float* __restrict__ a, const float* __restrict__ mask,
                           const float* __restrict__ b2d, float* __restrict__ d,
                           float* __restrict__ partials0) {
    __shared__ float red[8];
    const int b = blockIdx.y;
    const int i0 = (blockIdx.x * 256 + threadIdx.x) * 4;
    const float bb = b2d[0];
    const float* a0p = a + (b * 2 + 0) * 2000;
    const float* a1p = a + (b * 2 + 1) * 2000;
    const float4 m0 = *(const float4*)(mask + (size_t)(b * 2 + 0) * 256000 + i0);
    const float4 m1 = *(const float4*)(mask + (size_t)(b * 2 + 1) * 256000 + i0);
    float* dp = d + (size_t)b * 256000;
    float mv0[4] = {m0.x, m0.y, m0.z, m0.w};
    float mv1[4] = {m1.x, m1.y, m1.z, m1.w};
    float dv[4];
    float s = 0.f, q = 0.f;
    #pragma unroll
    for (int j = 0; j < 4; j++) {
        int t = (i0 + j) % 2000;
        float v = fmaf(a0p[t], mv0[j], a1p[t] * mv1[j]) + bb;
        dv[j] = v;
        s += v; q = fmaf(v, v, q);
    }
    *(float4*)(dp + i0) = *(float4*)dv;
    block_reduce2(s, q, red);
    if (threadIdx.x == 0) {
        partials0[(b * 256 + blockIdx.x) * 2]     = s;
        partials0[(b * 256 + blockIdx.x) * 2 + 1] = q;
    }
}

// MFMA conv: Y[o,t] = bias[o] + sum_k W[o,k]*X[k,t], k=f*3+kk,
// X[k,t] = leaky(LN(xin[f, 2t-1+kk])). 16x16x32 bf16 MFMA.
// Block: 256 thr (4 waves), M = 256/SPLITM output rows, NT=32 t-cols, full K.
// grid ((TOUT/32 rounded up)*SPLITM, 4). Writes 64 stat-partials per b.
template <int CIN, int TIN, int TOUT, int SPLITM, bool PERCH>
__launch_bounds__(256)
__global__ void kconv(const float* __restrict__ xin, const float* __restrict__ pin,
                      int pin_bstride, int npin, float nrm,
                      const float* __restrict__ gam, const float* __restrict__ bet,
                      const ushortT* __restrict__ wb, const float* __restrict__ bias,
                      float* __restrict__ yout, float* __restrict__ pout) {
    constexpr int K = CIN * 3;
    constexpr int ROWB = K * 2;          // LDS bytes per t-row (bf16)
    constexpr int NT = 32;
    constexpr int MPB = 256 / SPLITM;    // output rows per block
    constexpr int MF = MPB / 64;         // m-frags per wave
    __shared__ uint4 Xs4[NT * ROWB / 16];
    __shared__ float red[8];
    __shared__ float stat[2];
    char* Xs = (char*)Xs4;

    const int b = blockIdx.y;
    const int ms = blockIdx.x % SPLITM;
    const int tile = blockIdx.x / SPLITM;
    const int t0 = tile * NT;
    const int lane = threadIdx.x & 63;
    const int wv = threadIdx.x >> 6;

    stats_from_partials(pin + b * pin_bstride, npin, nrm, red, stat);
    const float mean = stat[0], inv = stat[1];

    // ---- stage X tile: columns c in [0,65), c -> ti = 2*t0-1+c ----
    const int base_ti = 2 * t0 - 1;
    for (int f = wv; f < CIN; f += 4) {
        int ti = base_ti + lane;
        float v = 0.f;
        if (ti >= 0 && ti < TIN) {
            float raw = xin[((size_t)b * CIN + f) * TIN + ti];
            float gg = PERCH ? gam[f] : gam[0];
            float bb = PERCH ? bet[f] : bet[0];
            v = leaky(fmaf(gg * inv, raw - mean, bb));
        }
        ushortT bv = f2bf(v);
        int c = lane;
        if (c & 1) {                       // ti even -> kk=1 at t=(c-1)/2
            int t = (c - 1) >> 1;
            int ad = t * ROWB + (f * 3 + 1) * 2; ad ^= (t & 7) << 4;
            *(ushortT*)(Xs + ad) = bv;
        } else {                           // ti odd -> kk=0 at t=c/2, kk=2 at t=c/2-1
            int t = c >> 1;
            int ad = t * ROWB + (f * 3 + 0) * 2; ad ^= (t & 7) << 4;
            *(ushortT*)(Xs + ad) = bv;
            if (t >= 1) {
                int t2 = t - 1;
                int ad2 = t2 * ROWB + (f * 3 + 2) * 2; ad2 ^= (t2 & 7) << 4;
                *(ushortT*)(Xs + ad2) = bv;
            }
        }
    }
    // edge column c = 64 -> kk=2 at t = NT-1
    if ((int)threadIdx.x < CIN) {
        int f = threadIdx.x;
        int ti = base_ti + 64;
        float v = 0.f;
        if (ti < TIN) {
            float raw = xin[((size_t)b * CIN + f) * TIN + ti];
            float gg = PERCH ? gam[f] : gam[0];
            float bb = PERCH ? bet[f] : bet[0];
            v = leaky(fmaf(gg * inv, raw - mean, bb));
        }
        int t = NT - 1;
        int ad = t * ROWB + (f * 3 + 2) * 2; ad ^= (t & 7) << 4;
        *(ushortT*)(Xs + ad) = f2bf(v);
    }
    __syncthreads();

    // ---- MFMA main loop ----
    const int obase = ms * MPB + wv * (MPB / 4);
    f32x4 acc[MF][2];
    #pragma unroll
    for (int mf = 0; mf < MF; mf++)
        #pragma unroll
        for (int nf = 0; nf < 2; nf++)
            acc[mf][nf] = (f32x4){0.f, 0.f, 0.f, 0.f};

    const int kgrp = (lane >> 4) * 8;
    const int mrow = lane & 15;
    #pragma unroll 2
    for (int ks = 0; ks < K / 32; ks++) {
        int kb = ks * 32 + kgrp;
        B8 afr[MF];
        #pragma unroll
        for (int mf = 0; mf < MF; mf++)
            afr[mf].u = *(const uint4*)(wb + (size_t)(obase + mf * 16 + mrow) * K + kb);
        #pragma unroll
        for (int nf = 0; nf < 2; nf++) {
            int t = nf * 16 + mrow;
            int ad = t * ROWB + kb * 2; ad ^= (t & 7) << 4;
            B8 bfr; bfr.u = *(const uint4*)(Xs + ad);
            #pragma unroll
            for (int mf = 0; mf < MF; mf++)
                acc[mf][nf] = __builtin_amdgcn_mfma_f32_16x16x32_bf16(
                    afr[mf].v, bfr.v, acc[mf][nf], 0, 0, 0);
        }
    }

    // ---- epilogue: bias, store, stat partials ----
    float s = 0.f, q = 0.f;
    #pragma unroll
    for (int mf = 0; mf < MF; mf++) {
        int orow0 = obase + mf * 16 + (lane >> 4) * 4;
        #pragma unroll
        for (int nf = 0; nf < 2; nf++) {
            int t = t0 + nf * 16 + mrow;
            if (t < TOUT) {
                #pragma unroll
                for (int r = 0; r < 4; r++) {
                    float v = acc[mf][nf][r] + bias[orow0 + r];
                    yout[((size_t)b * 256 + orow0 + r) * TOUT + t] = v;
                    s += v; q = fmaf(v, v, q);
                }
            }
        }
    }
    block_reduce2(s, q, red);
    if (threadIdx.x == 0) {
        int bi = b * 64 + tile * SPLITM + ms;
        pout[bi * 2]     = s;
        pout[bi * 2 + 1] = q;
    }
}

// K5: out[b,0,t] = b3 + sum_o w3[o]*leaky(LN2(y2[b,o,t])). grid (8,4),
// 64 t-lanes x 4 o-chunks, LDS combine.
__global__ void k5_conv3(const float* __restrict__ y2, const float* __restrict__ partials2,
                         const float* __restrict__ g2, const float* __restrict__ bb2,
                         const float* __restrict__ w3, const float* __restrict__ b3,
                         float* __restrict__ out) {
    __shared__ float red[8];
    __shared__ float stat[2];
    __shared__ float part[4][64];
    const int b = blockIdx.y;
    stats_from_partials(partials2 + b * 128, 64, 1.f / 128000.f, red, stat);
    const float mean = stat[0], inv = stat[1];
    const int tl = threadIdx.x & 63, fg = threadIdx.x >> 6;
    const int t = blockIdx.x * 64 + tl;
    float acc = 0.f;
    if (t < 500) {
        const float* yb = y2 + ((size_t)b * 256 + fg * 64) * 500 + t;
        #pragma unroll 8
        for (int i = 0; i < 64; i++) {
            int o = fg * 64 + i;
            float raw = yb[i * 500];
            float xv = leaky(fmaf(g2[o] * inv, raw - mean, bb2[o]));
            acc = fmaf(w3[o], xv, acc);
        }
    }
    part[fg][tl] = acc;
    __syncthreads();
    if (fg == 0 && t < 500)
        out[b * 500 + t] = b3[0] + part[0][tl] + part[1][tl] + part[2][tl] + part[3][tl];
}

extern "C" void kernel_launch(void* const* d_in, const int* in_sizes, int n_in,
                              void* d_out, int out_size, void* d_ws, size_t ws_size,
                              hipStream_t stream) {
    const float* feature = (const float*)d_in[0];
    const float* mask    = (const float*)d_in[1];
    const float* w2d     = (const float*)d_in[2];
    const float* b2d     = (const float*)d_in[3];
    const float* g2d     = (const float*)d_in[4];
    const float* be2d    = (const float*)d_in[5];
    const float* w1      = (const float*)d_in[6];
    const float* b1      = (const float*)d_in[7];
    const float* g1      = (const float*)d_in[8];
    const float* bb1     = (const float*)d_in[9];
    const float* w2      = (const float*)d_in[10];
    const float* b2      = (const float*)d_in[11];
    const float* g2      = (const float*)d_in[12];
    const float* bb2     = (const float*)d_in[13];
    const float* w3      = (const float*)d_in[14];
    const float* b3      = (const float*)d_in[15];
    float* out = (float*)d_out;

    float* ws = (float*)d_ws;
    float* partials0 = ws;               // 4*512 = 2048
    float* partials1 = ws + 2048;        // 4*128 = 512
    float* partials2 = ws + 2560;        // 4*128 = 512
    float* a   = ws + 3072;              // 16000
    float* d   = a + 16000;              // 1,024,000
    float* y1  = d + 1024000;            // 1,024,000
    float* y2  = y1 + 1024000;           // 512,000
    ushortT* w1b = (ushortT*)(y2 + 512000);   // 98304 ushorts
    ushortT* w2b = w1b + 98304;               // 196608 ushorts

    // K1 computes a[] and converts weights to bf16 (fused prep blocks).
    k1_mix<<<dim3(63 + 72, 4), 256, 0, stream>>>(feature, w2d, a, w1, w2, w1b, w2b);
    k2_maskmix<<<dim3(250, 4), 256, 0, stream>>>(a, mask, b2d, d, partials0);
    // conv1: CIN=128, 2000->1000, SPLITM=2 -> grid (32*2, 4) = 256 blocks
    kconv<128, 2000, 1000, 2, false><<<dim3(64, 4), 256, 0, stream>>>(
        d, partials0, 512, 250, 1.f / 256000.f, g2d, be2d, w1b, b1, y1, partials1);
    // conv2: CIN=256, 1000->500, SPLITM=4 -> grid (16*4, 4) = 256 blocks
    kconv<256, 1000, 500, 4, true><<<dim3(64, 4), 256, 0, stream>>>(
        y1, partials1, 128, 64, 1.f / 256000.f, g1, bb1, w2b, b2, y2, partials2);
    k5_conv3<<<dim3(8, 4), 256, 0, stream>>>(y2, partials2, g2, bb2, w3, b3, out);
}